// Round 1
// baseline (3219.914 us; speedup 1.0000x reference)
//
#include <hip/hip_runtime.h>

// Child-Sum Tree-LSTM, level-synchronous, B=8 L=8192 D=768.
// Flattened rows: children of output row m are input rows 2m, 2m+1.
// Per level, fused kernel computes 6 GEMM products (K=768) + LSTM cell epilogue.
// fp16 MFMA (16x16x32), fp32 accum; c kept fp32, h kept fp16 between levels.

typedef _Float16 half8 __attribute__((ext_vector_type(8)));
typedef _Float16 half4v __attribute__((ext_vector_type(4)));
typedef float f32x4 __attribute__((ext_vector_type(4)));

#define ROWB 1536  // bytes per 768-elem fp16 row

__device__ __forceinline__ float sigm(float x) { return 1.f / (1.f + __expf(-x)); }
__device__ __forceinline__ float tanhfast(float x) { return 1.f - 2.f / (1.f + __expf(2.f * x)); }

// Build combined weights once per launch:
//   Acomb rows [0,2304)  = 0.5*W_iou + U_iou   (i,o,u)
//   Acomb rows [2304,3072) = 0.5*W_f           (wfx)
//   Ufb = U_f
__global__ void prep_weights(const float* __restrict__ Wiou, const float* __restrict__ Uiou,
                             const float* __restrict__ Wf, const float* __restrict__ Uf,
                             _Float16* __restrict__ Acomb, _Float16* __restrict__ Ufb)
{
    const int nA = 3072 * 768, nU = 768 * 768;
    int stride = gridDim.x * blockDim.x;
    for (int idx = blockIdx.x * blockDim.x + threadIdx.x; idx < nA + nU; idx += stride) {
        if (idx < nA) {
            int g = idx / 768, k = idx - g * 768;
            float v = (g < 2304) ? __fmaf_rn(0.5f, Wiou[idx], Uiou[idx])
                                 : 0.5f * Wf[(g - 2304) * 768 + k];
            Acomb[idx] = (_Float16)v;
        } else {
            Ufb[idx - nA] = (_Float16)Uf[idx - nA];
        }
    }
}

__global__ void cast_leaves(const float* __restrict__ x, _Float16* __restrict__ h, int n4)
{
    int stride = gridDim.x * blockDim.x;
    for (int i = blockIdx.x * blockDim.x + threadIdx.x; i < n4; i += stride) {
        float4 v = ((const float4*)x)[i];
        half4v o = { (_Float16)v.x, (_Float16)v.y, (_Float16)v.z, (_Float16)v.w };
        ((half4v*)h)[i] = o;
    }
}

// One tree level. Tile: 64 output nodes x 64 output cols, 4 waves (2x2), K=768.
// 6 acc groups: 0=i 1=o 2=u 3=wfx (A=hs), 4=fl (A=hl), 5=fr (A=hr).
// LDS tiles (each 64 rows x 64 fp16 = 8KB, XOR-swizzled rows):
//   0=HL 1=HR 2=Ai 3=Ao 4=Au 5=Aw 6=Uf
__global__ __launch_bounds__(256, 2) void tree_level(
    const _Float16* __restrict__ Hc, const float* __restrict__ Cc,
    const _Float16* __restrict__ Acomb, const _Float16* __restrict__ Ufb,
    const float* __restrict__ biou, const float* __restrict__ bfv,
    _Float16* __restrict__ Hn, float* __restrict__ Cn,
    float* __restrict__ outH, float* __restrict__ outC,
    int M, int firstLevel, int finalLevel)
{
    __shared__ __align__(16) char lds[7 * 8192];
    const int tid = threadIdx.x;
    const int lane = tid & 63;
    const int w = tid >> 6;
    const int wm = w >> 1, wd = w & 1;
    const int mBase = blockIdx.x * 64;
    const int d0 = blockIdx.y * 64;

    f32x4 acc[6][2][2];
#pragma unroll
    for (int g = 0; g < 6; ++g)
#pragma unroll
        for (int a = 0; a < 2; ++a)
#pragma unroll
            for (int b = 0; b < 2; ++b)
                acc[g][a][b] = (f32x4){0.f, 0.f, 0.f, 0.f};

    const int kb = (tid & 7) * 16;  // 16B chunk within a 128B row
    const int rhalf = tid >> 3;     // 0..31

    for (int kt = 0; kt < 768; kt += 64) {
        // ---- stage: issue global loads first (overlap w/ previous compute) ----
        uint4 v[14];
#pragma unroll
        for (int p = 0; p < 2; ++p) {
            const int rr = p * 32 + rhalf;
            const size_t colb = (size_t)kt * 2 + kb;
            const char* hbase = (const char*)Hc + (size_t)(2 * (mBase + rr)) * ROWB + colb;
            v[p * 7 + 0] = *(const uint4*)(hbase);          // HL row 2m
            v[p * 7 + 1] = *(const uint4*)(hbase + ROWB);   // HR row 2m+1
#pragma unroll
            for (int g2 = 0; g2 < 4; ++g2)
                v[p * 7 + 2 + g2] = *(const uint4*)((const char*)Acomb +
                                     (size_t)(g2 * 768 + d0 + rr) * ROWB + colb);
            v[p * 7 + 6] = *(const uint4*)((const char*)Ufb + (size_t)(d0 + rr) * ROWB + colb);
        }
        __syncthreads();  // previous compute done reading LDS
#pragma unroll
        for (int p = 0; p < 2; ++p) {
            const int rr = p * 32 + rhalf;
            const int wofs = rr * 128 + (kb ^ ((rr & 7) << 4));
#pragma unroll
            for (int t = 0; t < 7; ++t)
                *(uint4*)(lds + t * 8192 + wofs) = v[p * 7 + t];
        }
        __syncthreads();

        // ---- compute ----
#pragma unroll
        for (int ks = 0; ks < 2; ++ks) {
            const int kbyte = ks * 64 + ((lane >> 4) * 16);
            half8 hl[2], hr[2], hs[2];
#pragma unroll
            for (int fm = 0; fm < 2; ++fm) {
                int r = wm * 32 + fm * 16 + (lane & 15);
                int off = r * 128 + (kbyte ^ ((r & 7) << 4));
                hl[fm] = *(const half8*)(lds + 0 * 8192 + off);
                hr[fm] = *(const half8*)(lds + 1 * 8192 + off);
                hs[fm] = hl[fm] + hr[fm];  // v_pk_add_f16
            }
            half8 bm[5][2];
#pragma unroll
            for (int t = 0; t < 5; ++t)
#pragma unroll
                for (int fd = 0; fd < 2; ++fd) {
                    int r = wd * 32 + fd * 16 + (lane & 15);
                    int off = r * 128 + (kbyte ^ ((r & 7) << 4));
                    bm[t][fd] = *(const half8*)(lds + (2 + t) * 8192 + off);
                }
#pragma unroll
            for (int fm = 0; fm < 2; ++fm)
#pragma unroll
                for (int fd = 0; fd < 2; ++fd) {
                    acc[0][fm][fd] = __builtin_amdgcn_mfma_f32_16x16x32_f16(hs[fm], bm[0][fd], acc[0][fm][fd], 0, 0, 0);
                    acc[1][fm][fd] = __builtin_amdgcn_mfma_f32_16x16x32_f16(hs[fm], bm[1][fd], acc[1][fm][fd], 0, 0, 0);
                    acc[2][fm][fd] = __builtin_amdgcn_mfma_f32_16x16x32_f16(hs[fm], bm[2][fd], acc[2][fm][fd], 0, 0, 0);
                    acc[3][fm][fd] = __builtin_amdgcn_mfma_f32_16x16x32_f16(hs[fm], bm[3][fd], acc[3][fm][fd], 0, 0, 0);
                    acc[4][fm][fd] = __builtin_amdgcn_mfma_f32_16x16x32_f16(hl[fm], bm[4][fd], acc[4][fm][fd], 0, 0, 0);
                    acc[5][fm][fd] = __builtin_amdgcn_mfma_f32_16x16x32_f16(hr[fm], bm[4][fd], acc[5][fm][fd], 0, 0, 0);
                }
        }
    }

    // ---- LSTM cell epilogue, all in-register ----
#pragma unroll
    for (int fm = 0; fm < 2; ++fm) {
#pragma unroll
        for (int fd = 0; fd < 2; ++fd) {
#pragma unroll
            for (int r4 = 0; r4 < 4; ++r4) {
                int row = mBase + wm * 32 + fm * 16 + ((lane >> 4) * 4) + r4;
                int col = d0 + wd * 32 + fd * 16 + (lane & 15);
                if (row < M) {
                    float iv = acc[0][fm][fd][r4] + biou[col];
                    float ov = acc[1][fm][fd][r4] + biou[768 + col];
                    float uv = acc[2][fm][fd][r4] + biou[1536 + col];
                    float wv = acc[3][fm][fd][r4] + bfv[col];
                    float fl = sigm(wv + acc[4][fm][fd][r4]);
                    float fr = sigm(wv + acc[5][fm][fd][r4]);
                    float cl = 0.f, cr = 0.f;
                    if (!firstLevel) {
                        cl = Cc[(size_t)(2 * row) * 768 + col];
                        cr = Cc[(size_t)(2 * row + 1) * 768 + col];
                    }
                    float c = sigm(iv) * tanhfast(uv) + fl * cl + fr * cr;
                    float h = sigm(ov) * tanhfast(c);
                    if (finalLevel) {
                        outH[row * 768 + col] = h;
                        outC[row * 768 + col] = c;
                    } else {
                        Hn[(size_t)row * 768 + col] = (_Float16)h;
                        Cn[(size_t)row * 768 + col] = c;
                    }
                }
            }
        }
    }
}

extern "C" void kernel_launch(void* const* d_in, const int* in_sizes, int n_in,
                              void* d_out, int out_size, void* d_ws, size_t ws_size,
                              hipStream_t stream)
{
    const float* leaf = (const float*)d_in[0];
    const float* Wiou = (const float*)d_in[1];
    const float* biou = (const float*)d_in[2];
    const float* Uiou = (const float*)d_in[3];
    const float* Wf   = (const float*)d_in[4];
    const float* bfv  = (const float*)d_in[5];
    const float* Uf   = (const float*)d_in[6];

    char* ws = (char*)d_ws;
    _Float16* Acomb = (_Float16*)(ws);                 // 3072x768 fp16 = 4,718,592 B
    _Float16* Ufb   = (_Float16*)(ws + 4718592);       //  768x768 fp16 = 1,179,648 B
    _Float16* H0    = (_Float16*)(ws + 5898240);       // 65536x768 fp16 = 100,663,296 B
    _Float16* H1    = (_Float16*)(ws + 106561536);     // 32768x768 fp16 =  50,331,648 B
    float*    C0    = (float*)(ws + 156893184);        // 32768x768 f32  = 100,663,296 B
    float*    C1    = (float*)(ws + 257556480);        // 16384x768 f32  =  50,331,648 B
    // total ws use: 307,888,128 bytes

    prep_weights<<<1024, 256, 0, stream>>>(Wiou, Uiou, Wf, Uf, Acomb, Ufb);
    cast_leaves<<<2048, 256, 0, stream>>>(leaf, H0, 50331648 / 4);

    float* out = (float*)d_out;  // [2, 8, 768]: out[0..6143]=h_root, out[6144..]=c_root
    _Float16* Hc = H0; _Float16* Hn = H1;
    float* Cc = C1; float* Cn = C0;
    int rows = 65536, level = 0;
    while (rows > 8) {
        int M = rows >> 1;
        int fin = (M == 8) ? 1 : 0;
        dim3 grid((M + 63) / 64, 12);
        tree_level<<<grid, 256, 0, stream>>>(Hc, Cc, Acomb, Ufb, biou, bfv,
            Hn, Cn, fin ? out : (float*)nullptr, fin ? out + 6144 : (float*)nullptr,
            M, level == 0 ? 1 : 0, fin);
        _Float16* th = Hc; Hc = Hn; Hn = th;
        float* tc = Cc; Cc = Cn; Cn = tc;
        rows = M; ++level;
    }
}

// Round 2
// 1229.063 us; speedup vs baseline: 2.6198x; 2.6198x over previous
//
#include <hip/hip_runtime.h>

// Child-Sum Tree-LSTM, level-synchronous, B=8 L=8192 D=768.
// Per level: 6 K=768 GEMM products fused with the LSTM cell epilogue.
// fp16 MFMA 16x16x32, fp32 accum. Block = 64 out-rows x 192 out-cols,
// 512 threads (waves 2x4). K-tiles of 32, double-buffered LDS staged via
// global_load_lds with source-side XOR swizzle (linear LDS dest).

typedef _Float16 half8 __attribute__((ext_vector_type(8)));
typedef _Float16 half4v __attribute__((ext_vector_type(4)));
typedef float f32x4 __attribute__((ext_vector_type(4)));

#define ROWB 1536      // bytes per 768-elem fp16 row
#define NT 24          // 768 / 32
#define BUFB 69632     // per LDS buffer: A 8192 + B 61440
#define BOFF 8192

__device__ __forceinline__ float sigm(float x){ return 1.f/(1.f+__expf(-x)); }
__device__ __forceinline__ float tanhfast(float x){ return 1.f - 2.f/(1.f+__expf(2.f*x)); }

__device__ __forceinline__ void gload16(const void* g, void* l){
  __builtin_amdgcn_global_load_lds((const __attribute__((address_space(1))) void*)g,
                                   (__attribute__((address_space(3))) void*)l, 16, 0, 0);
}

// Acomb rows [0,2304) = 0.5*W_iou + U_iou ; rows [2304,3072) = 0.5*W_f ; Ufb = U_f
__global__ void prep_weights(const float* __restrict__ Wiou, const float* __restrict__ Uiou,
                             const float* __restrict__ Wf, const float* __restrict__ Uf,
                             _Float16* __restrict__ Acomb, _Float16* __restrict__ Ufb)
{
    const int nA = 3072 * 768, nU = 768 * 768;
    int stride = gridDim.x * blockDim.x;
    for (int idx = blockIdx.x * blockDim.x + threadIdx.x; idx < nA + nU; idx += stride) {
        if (idx < nA) {
            int g = idx / 768, k = idx - g * 768;
            float v = (g < 2304) ? __fmaf_rn(0.5f, Wiou[idx], Uiou[idx])
                                 : 0.5f * Wf[(g - 2304) * 768 + k];
            Acomb[idx] = (_Float16)v;
        } else {
            Ufb[idx - nA] = (_Float16)Uf[idx - nA];
        }
    }
}

__global__ void cast_leaves(const float* __restrict__ x, _Float16* __restrict__ h, int n4)
{
    int stride = gridDim.x * blockDim.x;
    for (int i = blockIdx.x * blockDim.x + threadIdx.x; i < n4; i += stride) {
        float4 v = ((const float4*)x)[i];
        half4v o = { (_Float16)v.x, (_Float16)v.y, (_Float16)v.z, (_Float16)v.w };
        ((half4v*)h)[i] = o;
    }
}

// LDS layout per buffer:
//  A: 64 rows x 128B. Row r chunk j (16B) holds: jj=j^(r&7); side=jj>>2 (0=HL,1=HR),
//     kchunk=jj&3 of global H row 2*(mBase+r)+side.
//  B: 5 mats x 96 pairs x 128B. Pair p chunk j: jj=j^(p&7); col=d0+2p+(jj>>2),
//     kchunk=jj&3 of weight row `col`.
__global__ __launch_bounds__(512) void tree_level(
    const _Float16* __restrict__ Hc, const float* __restrict__ Cc,
    const _Float16* __restrict__ Acomb, const _Float16* __restrict__ Ufb,
    const float* __restrict__ biou, const float* __restrict__ bfv,
    _Float16* __restrict__ Hn, float* __restrict__ Cn,
    float* __restrict__ outH, float* __restrict__ outC,
    int M, int mblocks, int firstLevel, int finalLevel)
{
    __shared__ __align__(16) char smem[2 * BUFB];
    const int tid = threadIdx.x;
    const int lane = tid & 63;
    const int w = tid >> 6;        // 0..7
    const int wm = w >> 2;         // 0..1 row-wave
    const int wd = w & 3;          // 0..3 col-wave

    // XCD-aware decode: group same-d0 blocks onto XCD pairs (B slice 1.47MB < 4MB L2)
    int v = blockIdx.x;
    if ((mblocks & 1) == 0) { int per = (mblocks * 4) >> 3; v = (v & 7) * per + (v >> 3); }
    const int d0c = v / mblocks;
    const int mb = v - d0c * mblocks;
    const int mBase = mb * 64;
    const int d0 = d0c * 192;

    // ---- stage-slot precompute (9 slots/wave, all compile-time indexed) ----
    const int l3 = lane >> 3, j = lane & 7;
    const char* src[9];
    int dst[9];
#pragma unroll
    for (int s = 0; s < 9; ++s) {
        int u = s * 8 + w;
        src[s] = nullptr; dst[s] = 0;
        if (u < 68) {
            if (u < 8) {           // A instr: 8 dest rows each
                int rA = u * 8 + l3;
                int jj = j ^ (rA & 7);
                src[s] = (const char*)Hc + (size_t)(2 * (mBase + rA) + (jj >> 2)) * ROWB + (jj & 3) * 16;
                dst[s] = u * 1024;
            } else {               // B instr: 8 dest pairs each
                int i = u - 8, t = i / 12, pb = (i - t * 12) * 8, p = pb + l3;
                int jj = j ^ (p & 7);
                int cl = 2 * p + (jj >> 2);
                src[s] = ((t < 4) ? (const char*)Acomb + (size_t)(t * 768 + d0 + cl) * ROWB
                                  : (const char*)Ufb + (size_t)(d0 + cl) * ROWB) + (jj & 3) * 16;
                dst[s] = BOFF + t * 12288 + pb * 128;
            }
        }
    }
#define STAGE(buf, ko) do { _Pragma("unroll") for (int s = 0; s < 9; ++s) { \
        int u = s * 8 + w; if (u < 68) gload16(src[s] + (ko), smem + (buf) * BUFB + dst[s]); } } while (0)

    // ---- compute-offset precompute (kt-invariant) ----
    const int q = lane >> 4;       // 0..3 K-slice / C-row-group
    const int lr = lane & 15;
    int offA[2], offB3[3];
#pragma unroll
    for (int fm = 0; fm < 2; ++fm) {
        int r = wm * 32 + fm * 16 + lr;
        offA[fm] = r * 128 + ((q ^ (r & 7)) * 16);
    }
#pragma unroll
    for (int fd = 0; fd < 3; ++fd) {
        int cl = wd * 48 + fd * 16 + lr;
        int p = cl >> 1;
        int jb = ((cl & 1) * 4 + q) ^ (p & 7);
        offB3[fd] = BOFF + p * 128 + jb * 16;
    }

    f32x4 acc[6][2][3];
#pragma unroll
    for (int g = 0; g < 6; ++g)
#pragma unroll
        for (int a = 0; a < 2; ++a)
#pragma unroll
            for (int b = 0; b < 3; ++b)
                acc[g][a][b] = (f32x4){0.f, 0.f, 0.f, 0.f};

    // ---- main K loop: stage(kt+1) issued before compute(kt); 1 barrier/kt ----
    STAGE(0, 0);
    __syncthreads();
    for (int kt = 0; kt < NT; ++kt) {
        const int cur = kt & 1;
        if (kt + 1 < NT) STAGE(cur ^ 1, (size_t)(kt + 1) * 64);
        const char* bb = smem + cur * BUFB;
        half8 hl[2], hr[2], hs[2];
#pragma unroll
        for (int fm = 0; fm < 2; ++fm) {
            hl[fm] = *(const half8*)(bb + offA[fm]);
            hr[fm] = *(const half8*)(bb + (offA[fm] ^ 64));
            hs[fm] = hl[fm] + hr[fm];
        }
#pragma unroll
        for (int fd = 0; fd < 3; ++fd) {
            const char* bp = bb + offB3[fd];
            half8 b0 = *(const half8*)(bp);
            half8 b1 = *(const half8*)(bp + 12288);
            half8 b2 = *(const half8*)(bp + 2 * 12288);
            half8 b3 = *(const half8*)(bp + 3 * 12288);
            half8 b4 = *(const half8*)(bp + 4 * 12288);
#pragma unroll
            for (int fm = 0; fm < 2; ++fm) {
                acc[0][fm][fd] = __builtin_amdgcn_mfma_f32_16x16x32_f16(hs[fm], b0, acc[0][fm][fd], 0, 0, 0);
                acc[1][fm][fd] = __builtin_amdgcn_mfma_f32_16x16x32_f16(hs[fm], b1, acc[1][fm][fd], 0, 0, 0);
                acc[2][fm][fd] = __builtin_amdgcn_mfma_f32_16x16x32_f16(hs[fm], b2, acc[2][fm][fd], 0, 0, 0);
                acc[3][fm][fd] = __builtin_amdgcn_mfma_f32_16x16x32_f16(hs[fm], b3, acc[3][fm][fd], 0, 0, 0);
                acc[4][fm][fd] = __builtin_amdgcn_mfma_f32_16x16x32_f16(hl[fm], b4, acc[4][fm][fd], 0, 0, 0);
                acc[5][fm][fd] = __builtin_amdgcn_mfma_f32_16x16x32_f16(hr[fm], b4, acc[5][fm][fd], 0, 0, 0);
            }
        }
        if (kt + 1 < NT) __syncthreads();
    }

    // ---- LSTM cell epilogue, in-register ----
#pragma unroll
    for (int fd = 0; fd < 3; ++fd) {
        const int col = d0 + wd * 48 + fd * 16 + lr;
        const float bi = biou[col];
        const float bo = biou[768 + col];
        const float bu = biou[1536 + col];
        const float bf = bfv[col];
#pragma unroll
        for (int fm = 0; fm < 2; ++fm) {
            const int rbase = mBase + wm * 32 + fm * 16 + q * 4;
#pragma unroll
            for (int r4 = 0; r4 < 4; ++r4) {
                int row = rbase + r4;
                if (row < M) {
                    float iv = acc[0][fm][fd][r4] + bi;
                    float ov = acc[1][fm][fd][r4] + bo;
                    float uv = acc[2][fm][fd][r4] + bu;
                    float wv = acc[3][fm][fd][r4] + bf;
                    float fl = sigm(wv + acc[4][fm][fd][r4]);
                    float fr = sigm(wv + acc[5][fm][fd][r4]);
                    float clv = 0.f, crv = 0.f;
                    if (!firstLevel) {
                        clv = Cc[(size_t)(2 * row) * 768 + col];
                        crv = Cc[(size_t)(2 * row + 1) * 768 + col];
                    }
                    float c = sigm(iv) * tanhfast(uv) + fl * clv + fr * crv;
                    float h = sigm(ov) * tanhfast(c);
                    if (finalLevel) {
                        outH[row * 768 + col] = h;
                        outC[row * 768 + col] = c;
                    } else {
                        Hn[(size_t)row * 768 + col] = (_Float16)h;
                        Cn[(size_t)row * 768 + col] = c;
                    }
                }
            }
        }
    }
}

extern "C" void kernel_launch(void* const* d_in, const int* in_sizes, int n_in,
                              void* d_out, int out_size, void* d_ws, size_t ws_size,
                              hipStream_t stream)
{
    const float* leaf = (const float*)d_in[0];
    const float* Wiou = (const float*)d_in[1];
    const float* biou = (const float*)d_in[2];
    const float* Uiou = (const float*)d_in[3];
    const float* Wf   = (const float*)d_in[4];
    const float* bfv  = (const float*)d_in[5];
    const float* Uf   = (const float*)d_in[6];

    char* ws = (char*)d_ws;
    _Float16* Acomb = (_Float16*)(ws);               // 3072x768 fp16
    _Float16* Ufb   = (_Float16*)(ws + 4718592);     //  768x768 fp16
    _Float16* H0    = (_Float16*)(ws + 5898240);     // 65536x768 fp16
    _Float16* H1    = (_Float16*)(ws + 106561536);   // 32768x768 fp16
    float*    C0    = (float*)(ws + 156893184);      // 32768x768 f32
    float*    C1    = (float*)(ws + 257556480);      // 16384x768 f32

    prep_weights<<<1024, 256, 0, stream>>>(Wiou, Uiou, Wf, Uf, Acomb, Ufb);
    cast_leaves<<<2048, 256, 0, stream>>>(leaf, H0, 50331648 / 4);

    float* out = (float*)d_out;  // [2,8,768]
    _Float16* Hc = H0; _Float16* Hn = H1;
    float* Cc = C1; float* Cn = C0;
    int rows = 65536, level = 0;
    while (rows > 8) {
        int M = rows >> 1;
        int fin = (M == 8) ? 1 : 0;
        int mblocks = (M + 63) / 64;
        tree_level<<<mblocks * 4, 512, 0, stream>>>(Hc, Cc, Acomb, Ufb, biou, bfv,
            Hn, Cn, fin ? out : (float*)nullptr, fin ? out + 6144 : (float*)nullptr,
            M, mblocks, level == 0 ? 1 : 0, fin);
        _Float16* th = Hc; Hc = Hn; Hn = th;
        float* tc = Cc; Cc = Cn; Cn = tc;
        rows = M; ++level;
    }
}

// Round 3
// 1209.915 us; speedup vs baseline: 2.6613x; 1.0158x over previous
//
#include <hip/hip_runtime.h>

// Child-Sum Tree-LSTM, level-synchronous, B=8 L=8192 D=768.
// Per level: 6 K=768 GEMM products fused with the LSTM cell epilogue.
// fp16 MFMA 16x16x32, fp32 accum. Block = 64 out-rows x 128 out-cols,
// 512 threads (waves 2x4). K-tiles of 32, THREE-deep LDS pipeline staged via
// global_load_lds (source-side XOR swizzle, linear LDS dest), counted
// s_waitcnt vmcnt(12) + raw s_barrier pairs (no vmcnt(0) drain in the loop).

typedef _Float16 half8 __attribute__((ext_vector_type(8)));
typedef float f32x4 __attribute__((ext_vector_type(4)));

#define ROWB 1536      // bytes per 768-elem fp16 row
#define NT 24          // 768 / 32
#define BUFB 49152     // per LDS buffer: A 8192 + B 40960
#define BOFF 8192

__device__ __forceinline__ float sigm(float x){ return 1.f/(1.f+__expf(-x)); }
__device__ __forceinline__ float tanhfast(float x){ return 1.f - 2.f/(1.f+__expf(2.f*x)); }

__device__ __forceinline__ void gload16(const void* g, void* l){
  __builtin_amdgcn_global_load_lds((const __attribute__((address_space(1))) void*)g,
                                   (__attribute__((address_space(3))) void*)l, 16, 0, 0);
}

// Acomb rows [0,2304) = 0.5*W_iou + U_iou ; rows [2304,3072) = 0.5*W_f ; Ufb = U_f
__global__ void prep_weights(const float* __restrict__ Wiou, const float* __restrict__ Uiou,
                             const float* __restrict__ Wf, const float* __restrict__ Uf,
                             _Float16* __restrict__ Acomb, _Float16* __restrict__ Ufb)
{
    const int nA = 3072 * 768, nU = 768 * 768;
    int stride = gridDim.x * blockDim.x;
    for (int idx = blockIdx.x * blockDim.x + threadIdx.x; idx < nA + nU; idx += stride) {
        if (idx < nA) {
            int g = idx / 768, k = idx - g * 768;
            float v = (g < 2304) ? __fmaf_rn(0.5f, Wiou[idx], Uiou[idx])
                                 : 0.5f * Wf[(g - 2304) * 768 + k];
            Acomb[idx] = (_Float16)v;
        } else {
            Ufb[idx - nA] = (_Float16)Uf[idx - nA];
        }
    }
}

__global__ void cast_leaves(const float* __restrict__ x, _Float16* __restrict__ h, int n8)
{
    int stride = gridDim.x * blockDim.x;
    for (int i = blockIdx.x * blockDim.x + threadIdx.x; i < n8; i += stride) {
        float4 v0 = ((const float4*)x)[2 * i];
        float4 v1 = ((const float4*)x)[2 * i + 1];
        half8 o = { (_Float16)v0.x, (_Float16)v0.y, (_Float16)v0.z, (_Float16)v0.w,
                    (_Float16)v1.x, (_Float16)v1.y, (_Float16)v1.z, (_Float16)v1.w };
        ((half8*)h)[i] = o;
    }
}

// LDS layout per buffer:
//  A: 64 rows x 128B. Row r chunk j (16B): jj=j^(r&7); side=jj>>2 (0=HL,1=HR),
//     kchunk=jj&3 of global H row 2*(mBase+r)+side.
//  B: 5 mats x 64 pairs x 128B (mat stride 8192). Pair p chunk j: jj=j^(p&7);
//     col=d0+2p+(jj>>2), kchunk=jj&3 of weight row `col`.
__global__ __launch_bounds__(512, 2) void tree_level(
    const _Float16* __restrict__ Hc, const float* __restrict__ Cc,
    const _Float16* __restrict__ Acomb, const _Float16* __restrict__ Ufb,
    const float* __restrict__ biou, const float* __restrict__ bfv,
    _Float16* __restrict__ Hn, float* __restrict__ Cn,
    float* __restrict__ outH, float* __restrict__ outC,
    int M, int mblocks, int firstLevel, int finalLevel)
{
    __shared__ __align__(16) char smem[3 * BUFB];
    const int tid = threadIdx.x;
    const int lane = tid & 63;
    const int w = tid >> 6;        // 0..7
    const int wm = w >> 2;         // 0..1 row-wave
    const int wd = w & 3;          // 0..3 col-wave

    // bijective XCD chunking (m204): contiguous v-ranges (grouped by d0) per XCD
    const int nwg = mblocks * 6;
    const int orig = blockIdx.x;
    const int xcd = orig & 7, qx = nwg >> 3, rx = nwg & 7;
    const int v = (xcd < rx ? xcd * (qx + 1) : rx * (qx + 1) + (xcd - rx) * qx) + (orig >> 3);
    const int d0c = v / mblocks;
    const int mb = v - d0c * mblocks;
    const int mBase = mb * 64;
    const int d0 = d0c * 128;

    // ---- stage-slot precompute: 48 instr total, exactly 6 per wave ----
    const int l3 = lane >> 3, j = lane & 7;
    const char* src[6];
    int dst[6];
#pragma unroll
    for (int s = 0; s < 6; ++s) {
        int u = s * 8 + w;
        if (u < 8) {               // A: 8 instr, 8 rows each
            int rA = u * 8 + l3;
            int jj = j ^ (rA & 7);
            src[s] = (const char*)Hc + (size_t)(2 * (mBase + rA) + (jj >> 2)) * ROWB + (jj & 3) * 16;
            dst[s] = u * 1024;
        } else {                   // B: 40 instr, 8 pairs each
            int i = u - 8, t = i >> 3, pb = (i & 7) * 8, p = pb + l3;
            int jj = j ^ (p & 7);
            int cl = 2 * p + (jj >> 2);
            src[s] = ((t < 4) ? (const char*)Acomb + (size_t)(t * 768 + d0 + cl) * ROWB
                              : (const char*)Ufb + (size_t)(d0 + cl) * ROWB) + (jj & 3) * 16;
            dst[s] = BOFF + t * 8192 + pb * 128;
        }
    }
#define STAGE(bi, ko) do { _Pragma("unroll") for (int s = 0; s < 6; ++s) \
        gload16(src[s] + (ko), smem + (size_t)(bi) * BUFB + dst[s]); } while (0)

    // ---- compute-offset precompute (kt-invariant) ----
    const int q = lane >> 4;       // 0..3 K-slice / C-row-group
    const int lr = lane & 15;
    int offA[2], offB[2];
#pragma unroll
    for (int fm = 0; fm < 2; ++fm) {
        int r = wm * 32 + fm * 16 + lr;
        offA[fm] = r * 128 + ((q ^ (r & 7)) * 16);
    }
#pragma unroll
    for (int fd = 0; fd < 2; ++fd) {
        int cl = wd * 32 + fd * 16 + lr;
        int p = cl >> 1;
        int jb = ((cl & 1) * 4 + q) ^ (p & 7);
        offB[fd] = BOFF + p * 128 + jb * 16;
    }

    f32x4 acc[6][2][2];
#pragma unroll
    for (int g = 0; g < 6; ++g)
#pragma unroll
        for (int a = 0; a < 2; ++a)
#pragma unroll
            for (int b = 0; b < 2; ++b)
                acc[g][a][b] = (f32x4){0.f, 0.f, 0.f, 0.f};

    // ---- 3-deep pipeline: counted vmcnt, raw barriers, no full drain ----
    STAGE(0, 0);
    STAGE(1, 64);
    int cur = 0, stg = 2;
    for (int kt = 0; kt < NT; ++kt) {
        if (kt + 2 < NT) STAGE(stg, (kt + 2) * 64);
        if (kt + 2 < NT)      asm volatile("s_waitcnt vmcnt(12)" ::: "memory");
        else if (kt + 1 < NT) asm volatile("s_waitcnt vmcnt(6)" ::: "memory");
        else                  asm volatile("s_waitcnt vmcnt(0)" ::: "memory");
        __builtin_amdgcn_s_barrier();            // B1: group(kt) landed everywhere
        __builtin_amdgcn_sched_barrier(0);
        const char* bb = smem + (size_t)cur * BUFB;
        half8 hl[2], hr[2], hs[2];
#pragma unroll
        for (int fm = 0; fm < 2; ++fm) {
            hl[fm] = *(const half8*)(bb + offA[fm]);
            hr[fm] = *(const half8*)(bb + (offA[fm] ^ 64));
            hs[fm] = hl[fm] + hr[fm];
        }
        __builtin_amdgcn_s_setprio(1);
#pragma unroll
        for (int fd = 0; fd < 2; ++fd) {
            const char* bp = bb + offB[fd];
            half8 b0 = *(const half8*)(bp);
            half8 b1 = *(const half8*)(bp + 8192);
            half8 b2 = *(const half8*)(bp + 16384);
            half8 b3 = *(const half8*)(bp + 24576);
            half8 b4 = *(const half8*)(bp + 32768);
#pragma unroll
            for (int fm = 0; fm < 2; ++fm) {
                acc[0][fm][fd] = __builtin_amdgcn_mfma_f32_16x16x32_f16(hs[fm], b0, acc[0][fm][fd], 0, 0, 0);
                acc[1][fm][fd] = __builtin_amdgcn_mfma_f32_16x16x32_f16(hs[fm], b1, acc[1][fm][fd], 0, 0, 0);
                acc[2][fm][fd] = __builtin_amdgcn_mfma_f32_16x16x32_f16(hs[fm], b2, acc[2][fm][fd], 0, 0, 0);
                acc[3][fm][fd] = __builtin_amdgcn_mfma_f32_16x16x32_f16(hs[fm], b3, acc[3][fm][fd], 0, 0, 0);
                acc[4][fm][fd] = __builtin_amdgcn_mfma_f32_16x16x32_f16(hl[fm], b4, acc[4][fm][fd], 0, 0, 0);
                acc[5][fm][fd] = __builtin_amdgcn_mfma_f32_16x16x32_f16(hr[fm], b4, acc[5][fm][fd], 0, 0, 0);
            }
        }
        __builtin_amdgcn_s_setprio(0);
        if (kt + 1 < NT) __builtin_amdgcn_s_barrier();  // B2: all done reading buf[cur]
        cur = (cur + 1 == 3) ? 0 : cur + 1;
        stg = (stg + 1 == 3) ? 0 : stg + 1;
    }

    // ---- LSTM cell epilogue, in-register ----
#pragma unroll
    for (int fd = 0; fd < 2; ++fd) {
        const int col = d0 + wd * 32 + fd * 16 + lr;
        const float bi = biou[col];
        const float bo = biou[768 + col];
        const float bu = biou[1536 + col];
        const float bf = bfv[col];
#pragma unroll
        for (int fm = 0; fm < 2; ++fm) {
            const int rbase = mBase + wm * 32 + fm * 16 + q * 4;
#pragma unroll
            for (int r4 = 0; r4 < 4; ++r4) {
                int row = rbase + r4;
                if (row < M) {
                    float iv = acc[0][fm][fd][r4] + bi;
                    float ov = acc[1][fm][fd][r4] + bo;
                    float uv = acc[2][fm][fd][r4] + bu;
                    float wv = acc[3][fm][fd][r4] + bf;
                    float fl = sigm(wv + acc[4][fm][fd][r4]);
                    float fr = sigm(wv + acc[5][fm][fd][r4]);
                    float clv = 0.f, crv = 0.f;
                    if (!firstLevel) {
                        clv = Cc[(size_t)(2 * row) * 768 + col];
                        crv = Cc[(size_t)(2 * row + 1) * 768 + col];
                    }
                    float c = sigm(iv) * tanhfast(uv) + fl * clv + fr * crv;
                    float h = sigm(ov) * tanhfast(c);
                    if (finalLevel) {
                        outH[row * 768 + col] = h;
                        outC[row * 768 + col] = c;
                    } else {
                        Hn[(size_t)row * 768 + col] = (_Float16)h;
                        Cn[(size_t)row * 768 + col] = c;
                    }
                }
            }
        }
    }
}

extern "C" void kernel_launch(void* const* d_in, const int* in_sizes, int n_in,
                              void* d_out, int out_size, void* d_ws, size_t ws_size,
                              hipStream_t stream)
{
    const float* leaf = (const float*)d_in[0];
    const float* Wiou = (const float*)d_in[1];
    const float* biou = (const float*)d_in[2];
    const float* Uiou = (const float*)d_in[3];
    const float* Wf   = (const float*)d_in[4];
    const float* bfv  = (const float*)d_in[5];
    const float* Uf   = (const float*)d_in[6];

    char* ws = (char*)d_ws;
    _Float16* Acomb = (_Float16*)(ws);               // 3072x768 fp16
    _Float16* Ufb   = (_Float16*)(ws + 4718592);     //  768x768 fp16
    _Float16* H0    = (_Float16*)(ws + 5898240);     // 65536x768 fp16
    _Float16* H1    = (_Float16*)(ws + 106561536);   // 32768x768 fp16
    float*    C0    = (float*)(ws + 156893184);      // 32768x768 f32
    float*    C1    = (float*)(ws + 257556480);      // 16384x768 f32

    prep_weights<<<1024, 256, 0, stream>>>(Wiou, Uiou, Wf, Uf, Acomb, Ufb);
    cast_leaves<<<2048, 256, 0, stream>>>(leaf, H0, 50331648 / 8);

    float* out = (float*)d_out;  // [2,8,768]
    _Float16* Hc = H0; _Float16* Hn = H1;
    float* Cc = C1; float* Cn = C0;
    int rows = 65536, level = 0;
    while (rows > 8) {
        int M = rows >> 1;
        int fin = (M == 8) ? 1 : 0;
        int mblocks = (M + 63) / 64;
        tree_level<<<mblocks * 6, 512, 0, stream>>>(Hc, Cc, Acomb, Ufb, biou, bfv,
            Hn, Cn, fin ? out : (float*)nullptr, fin ? out + 6144 : (float*)nullptr,
            M, mblocks, level == 0 ? 1 : 0, fin);
        _Float16* th = Hc; Hc = Hn; Hn = th;
        float* tc = Cc; Cc = Cn; Cn = tc;
        rows = M; ++level;
    }
}

// Round 4
// 1063.770 us; speedup vs baseline: 3.0269x; 1.1374x over previous
//
#include <hip/hip_runtime.h>

// Child-Sum Tree-LSTM, level-synchronous, B=8 L=8192 D=768.
// Per level: 5 fused K=768 GEMM products + LSTM cell epilogue.
//   acc0..2 (i,o,u) = hs @ (0.5*W_iou + U_iou)^T
//   acc3 (fl-pre)   = hl@Wfp^T + hr@Wfh^T,  Wfp = 0.5*W_f + U_f, Wfh = 0.5*W_f
//   acc4 (fr-pre)   = hl@Wfh^T + hr@Wfp^T
// fp16 MFMA 16x16x32, fp32 accum. Block = 128 rows x 64 cols, 256 thr
// (4 waves 2x2, wave tile 64x32). Double-buffered 36.9KB LDS -> 2 blocks/CU
// for cross-block latency hiding. global_load_lds staging, source-side XOR
// swizzle, counted vmcnt(9), raw s_barrier pair per K-tile.

typedef _Float16 half8 __attribute__((ext_vector_type(8)));
typedef float f32x4 __attribute__((ext_vector_type(4)));

#define ROWB 1536        // bytes per 768-elem fp16 row
#define NT 24            // 768 / 32
#define BUFB 36864       // A 16384 + B 20480
#define MATB 1179648     // 768*768*2 bytes per weight mat

__device__ __forceinline__ float sigm(float x){ return 1.f/(1.f+__expf(-x)); }
__device__ __forceinline__ float tanhfast(float x){ return 1.f - 2.f/(1.f+__expf(2.f*x)); }

__device__ __forceinline__ void gload16(const void* g, void* l){
  __builtin_amdgcn_global_load_lds((const __attribute__((address_space(1))) void*)g,
                                   (__attribute__((address_space(3))) void*)l, 16, 0, 0);
}

// Bw: 5 mats of 768x768 fp16: [0..2]=0.5*W_iou+U_iou (i,o,u), [3]=0.5*Wf+Uf, [4]=0.5*Wf
__global__ void prep_weights(const float* __restrict__ Wiou, const float* __restrict__ Uiou,
                             const float* __restrict__ Wf, const float* __restrict__ Uf,
                             _Float16* __restrict__ Bw)
{
    const int n1 = 2304 * 768, n2 = n1 + 589824, n3 = n2 + 589824;
    int stride = gridDim.x * blockDim.x;
    for (int idx = blockIdx.x * blockDim.x + threadIdx.x; idx < n3; idx += stride) {
        float v;
        if (idx < n1)      v = __fmaf_rn(0.5f, Wiou[idx], Uiou[idx]);
        else if (idx < n2) { int k = idx - n1; v = __fmaf_rn(0.5f, Wf[k], Uf[k]); }
        else               { int k = idx - n2; v = 0.5f * Wf[k]; }
        Bw[idx] = (_Float16)v;
    }
}

__global__ void cast_leaves(const float* __restrict__ x, _Float16* __restrict__ h, int n8)
{
    int stride = gridDim.x * blockDim.x;
    for (int i = blockIdx.x * blockDim.x + threadIdx.x; i < n8; i += stride) {
        float4 v0 = ((const float4*)x)[2 * i];
        float4 v1 = ((const float4*)x)[2 * i + 1];
        half8 o = { (_Float16)v0.x, (_Float16)v0.y, (_Float16)v0.z, (_Float16)v0.w,
                    (_Float16)v1.x, (_Float16)v1.y, (_Float16)v1.z, (_Float16)v1.w };
        ((half8*)h)[i] = o;
    }
}

// LDS per buffer:
//  A: 128 rows x 128B. Row r chunk j: jj=j^(r&7); side=jj>>2 (0=HL,1=HR),
//     kchunk=jj&3 of H row 2*(mBase+r)+side.
//  B at +16384: 5 mats x 32 pairs x 128B (mat stride 4096). Pair p chunk j:
//     jj=j^(p&7); col=d0+2p+(jj>>2), kchunk=jj&3.
__global__ __launch_bounds__(256, 2) void tree_level(
    const _Float16* __restrict__ Hc, const float* __restrict__ Cc,
    const _Float16* __restrict__ Bw,
    const float* __restrict__ biou, const float* __restrict__ bfv,
    _Float16* __restrict__ Hn, float* __restrict__ Cn,
    float* __restrict__ outH, float* __restrict__ outC,
    int M, int mblocks, int firstLevel, int finalLevel)
{
    __shared__ __align__(16) char smem[2 * BUFB];
    const int tid = threadIdx.x;
    const int lane = tid & 63;
    const int w = tid >> 6;        // 0..3
    const int wm = w >> 1;         // 0..1 row-wave (64 rows each)
    const int wd = w & 1;          // 0..1 col-wave (32 cols each)

    // bijective XCD chunking: contiguous v-ranges (grouped by d0c) per XCD
    const int nwg = mblocks * 12;
    const int orig = blockIdx.x;
    const int xcd = orig & 7, qx = nwg >> 3, rx = nwg & 7;
    const int v = (xcd < rx ? xcd * (qx + 1) : rx * (qx + 1) + (xcd - rx) * qx) + (orig >> 3);
    const int d0c = v / mblocks;
    const int mb = v - d0c * mblocks;
    const int mBase = mb * 128;
    const int d0 = d0c * 64;

    // ---- stage-source precompute (compile-time A/B slot split: s<4 = A) ----
    const int l3 = lane >> 3, j = lane & 7;
    const int rbase = w * 8 + l3;          // 0..31
    const int jjA = j ^ l3;                // (rA&7) == l3 for all s
    unsigned offH[4];
#pragma unroll
    for (int s = 0; s < 4; ++s) {
        int gr = mBase + s * 32 + rbase;
        if (gr >= M) gr = M - 1;
        offH[s] = (unsigned)(2 * gr + (jjA >> 2)) * ROWB + (jjA & 3) * 16;
    }
    const int pB = w * 8 + l3;             // 0..31
    const int jjB = j ^ (pB & 7);
    const unsigned offWcol = (unsigned)(d0 + 2 * pB + (jjB >> 2)) * ROWB + (jjB & 3) * 16;
    const int wK = w * 1024;               // uniform part of LDS dest

#define STAGE(bi, ko) do { \
    _Pragma("unroll") for (int s = 0; s < 4; ++s) \
        gload16((const char*)Hc + offH[s] + (ko), smem + (bi) * BUFB + s * 4096 + wK); \
    _Pragma("unroll") for (int s = 0; s < 5; ++s) \
        gload16((const char*)Bw + (size_t)s * MATB + offWcol + (ko), \
                smem + (bi) * BUFB + 16384 + s * 4096 + wK); \
} while (0)

    // ---- compute offsets (kt-invariant) ----
    const int q = lane >> 4;       // K-slice / C-row-group
    const int lr = lane & 15;
    int offA[4], offB[2];
#pragma unroll
    for (int fm = 0; fm < 4; ++fm) {
        int r = wm * 64 + fm * 16 + lr;
        offA[fm] = r * 128 + ((q ^ (r & 7)) * 16);
    }
#pragma unroll
    for (int fd = 0; fd < 2; ++fd) {
        int cl = wd * 32 + fd * 16 + lr;
        int p = cl >> 1;
        int jb = ((cl & 1) * 4 + q) ^ (p & 7);
        offB[fd] = 16384 + p * 128 + jb * 16;
    }

    f32x4 acc[5][4][2];
#pragma unroll
    for (int g = 0; g < 5; ++g)
#pragma unroll
        for (int a = 0; a < 4; ++a)
#pragma unroll
            for (int b = 0; b < 2; ++b)
                acc[g][a][b] = (f32x4){0.f, 0.f, 0.f, 0.f};

    // ---- main loop: 2-deep, counted vmcnt, raw barriers ----
    STAGE(0, 0);
    int cur = 0;
    for (int kt = 0; kt < NT; ++kt) {
        if (kt + 1 < NT) {
            STAGE(cur ^ 1, (kt + 1) * 64);
            asm volatile("s_waitcnt vmcnt(9)" ::: "memory");
        } else {
            asm volatile("s_waitcnt vmcnt(0)" ::: "memory");
        }
        __builtin_amdgcn_s_barrier();          // buf[cur] landed for all waves
        __builtin_amdgcn_sched_barrier(0);
        const char* bb = smem + cur * BUFB;
        half8 hl[4], hr[4];
#pragma unroll
        for (int fm = 0; fm < 4; ++fm) {
            hl[fm] = *(const half8*)(bb + offA[fm]);
            hr[fm] = *(const half8*)(bb + (offA[fm] ^ 64));
        }
        __builtin_amdgcn_s_setprio(1);
#pragma unroll
        for (int fd = 0; fd < 2; ++fd) {
            const char* bp = bb + offB[fd];
            half8 b0 = *(const half8*)(bp);
            half8 b1 = *(const half8*)(bp + 4096);
            half8 b2 = *(const half8*)(bp + 8192);
            half8 b3 = *(const half8*)(bp + 12288);   // Wfp
            half8 b4 = *(const half8*)(bp + 16384);   // Wfh
#pragma unroll
            for (int fm = 0; fm < 4; ++fm) {
                half8 hs = hl[fm] + hr[fm];
                acc[0][fm][fd] = __builtin_amdgcn_mfma_f32_16x16x32_f16(hs, b0, acc[0][fm][fd], 0, 0, 0);
                acc[1][fm][fd] = __builtin_amdgcn_mfma_f32_16x16x32_f16(hs, b1, acc[1][fm][fd], 0, 0, 0);
                acc[2][fm][fd] = __builtin_amdgcn_mfma_f32_16x16x32_f16(hs, b2, acc[2][fm][fd], 0, 0, 0);
                acc[3][fm][fd] = __builtin_amdgcn_mfma_f32_16x16x32_f16(hl[fm], b3, acc[3][fm][fd], 0, 0, 0);
                acc[3][fm][fd] = __builtin_amdgcn_mfma_f32_16x16x32_f16(hr[fm], b4, acc[3][fm][fd], 0, 0, 0);
                acc[4][fm][fd] = __builtin_amdgcn_mfma_f32_16x16x32_f16(hl[fm], b4, acc[4][fm][fd], 0, 0, 0);
                acc[4][fm][fd] = __builtin_amdgcn_mfma_f32_16x16x32_f16(hr[fm], b3, acc[4][fm][fd], 0, 0, 0);
            }
        }
        __builtin_amdgcn_s_setprio(0);
        if (kt + 1 < NT) __builtin_amdgcn_s_barrier();  // done reading buf[cur]
        cur ^= 1;
    }

    // ---- LSTM cell epilogue, in-register ----
#pragma unroll
    for (int fd = 0; fd < 2; ++fd) {
        const int col = d0 + wd * 32 + fd * 16 + lr;
        const float bi = biou[col];
        const float bo = biou[768 + col];
        const float bu = biou[1536 + col];
        const float bf = bfv[col];
#pragma unroll
        for (int fm = 0; fm < 4; ++fm) {
            const int rb = mBase + wm * 64 + fm * 16 + q * 4;
#pragma unroll
            for (int r4 = 0; r4 < 4; ++r4) {
                int row = rb + r4;
                if (row < M) {
                    float iv = acc[0][fm][fd][r4] + bi;
                    float ov = acc[1][fm][fd][r4] + bo;
                    float uv = acc[2][fm][fd][r4] + bu;
                    float fl = sigm(acc[3][fm][fd][r4] + bf);
                    float fr = sigm(acc[4][fm][fd][r4] + bf);
                    float clv = 0.f, crv = 0.f;
                    if (!firstLevel) {
                        clv = Cc[(size_t)(2 * row) * 768 + col];
                        crv = Cc[(size_t)(2 * row + 1) * 768 + col];
                    }
                    float c = sigm(iv) * tanhfast(uv) + fl * clv + fr * crv;
                    float h = sigm(ov) * tanhfast(c);
                    if (finalLevel) {
                        outH[row * 768 + col] = h;
                        outC[row * 768 + col] = c;
                    } else {
                        Hn[(size_t)row * 768 + col] = (_Float16)h;
                        Cn[(size_t)row * 768 + col] = c;
                    }
                }
            }
        }
    }
}

extern "C" void kernel_launch(void* const* d_in, const int* in_sizes, int n_in,
                              void* d_out, int out_size, void* d_ws, size_t ws_size,
                              hipStream_t stream)
{
    const float* leaf = (const float*)d_in[0];
    const float* Wiou = (const float*)d_in[1];
    const float* biou = (const float*)d_in[2];
    const float* Uiou = (const float*)d_in[3];
    const float* Wf   = (const float*)d_in[4];
    const float* bfv  = (const float*)d_in[5];
    const float* Uf   = (const float*)d_in[6];

    char* ws = (char*)d_ws;
    _Float16* Bw = (_Float16*)(ws);                  // 5x768x768 fp16 = 5,898,240 B
    _Float16* H0 = (_Float16*)(ws + 5898240);        // 65536x768 fp16
    _Float16* H1 = (_Float16*)(ws + 106561536);      // 32768x768 fp16
    float*    C0 = (float*)(ws + 156893184);         // 32768x768 f32
    float*    C1 = (float*)(ws + 257556480);         // 16384x768 f32

    prep_weights<<<1024, 256, 0, stream>>>(Wiou, Uiou, Wf, Uf, Bw);
    cast_leaves<<<2048, 256, 0, stream>>>(leaf, H0, 50331648 / 8);

    float* out = (float*)d_out;  // [2,8,768]
    _Float16* Hc = H0; _Float16* Hn = H1;
    float* Cc = C1; float* Cn = C0;
    int rows = 65536, level = 0;
    while (rows > 8) {
        int M = rows >> 1;
        int fin = (M == 8) ? 1 : 0;
        int mblocks = (M + 127) / 128;
        tree_level<<<mblocks * 12, 256, 0, stream>>>(Hc, Cc, Bw, biou, bfv,
            Hn, Cn, fin ? out : (float*)nullptr, fin ? out + 6144 : (float*)nullptr,
            M, mblocks, level == 0 ? 1 : 0, fin);
        _Float16* th = Hc; Hc = Hn; Hn = th;
        float* tc = Cc; Cc = Cn; Cn = tc;
        rows = M; ++level;
    }
}